// Round 1
// baseline (1824.672 us; speedup 1.0000x reference)
//
#include <hip/hip_runtime.h>
#include <hip/hip_bf16.h>
#include <stdint.h>

// Problem constants
#define NB 1024           // batch
#define TT 4
#define DIN 768
#define DSAE 16384
#define KD (TT * DIN)     // 3072
#define KTOT 64

// ---------------- Kernel 1: fp32 GEMM  pre = relu(x * W_enc + b_enc) ----------------
// A: (NB, KD) row-major, W: (KD, DSAE) row-major, Z out: (NB, DSAE)
// 128x128 tile, BK=16, 256 threads, 8x8 micro-tile per thread.
// Accumulation is strictly sequential in k per output (matches np fp32 closely
// enough for stable top-k boundaries).
#define BM 128
#define BN 128
#define BKK 16

__global__ __launch_bounds__(256, 2) void gemm_relu_kernel(
    const float* __restrict__ A, const float* __restrict__ W,
    const float* __restrict__ benc, float* __restrict__ Z) {
  __shared__ float As[BKK][BM + 4];
  __shared__ float Bs[BKK][BN + 4];

  const int tid = threadIdx.x;
  const int bn = blockIdx.x;  // 0..127
  const int bm = blockIdx.y;  // 0..7
  const int M0 = bm * BM, N0 = bn * BN;
  const int tx = tid & 15, ty = tid >> 4;

  // A tile loader: 128 rows x 16 cols, float4 along k; 2 rows per thread
  const int ar = tid >> 2;            // 0..63
  const int ac = (tid & 3) << 2;      // 0,4,8,12
  // B tile loader: 16 rows x 128 cols, float4 along n; 2 rows per thread
  const int br = tid >> 5;            // 0..7
  const int bc = (tid & 31) << 2;     // 0..124

  float acc[8][8];
#pragma unroll
  for (int i = 0; i < 8; ++i)
#pragma unroll
    for (int j = 0; j < 8; ++j) acc[i][j] = 0.f;

  for (int k0 = 0; k0 < KD; k0 += BKK) {
    const float4 a0 = *(const float4*)&A[(size_t)(M0 + ar) * KD + k0 + ac];
    const float4 a1 = *(const float4*)&A[(size_t)(M0 + ar + 64) * KD + k0 + ac];
    const float4 b0 = *(const float4*)&W[(size_t)(k0 + br) * DSAE + N0 + bc];
    const float4 b1 = *(const float4*)&W[(size_t)(k0 + br + 8) * DSAE + N0 + bc];
    __syncthreads();  // previous iteration's LDS reads done
    As[ac + 0][ar] = a0.x; As[ac + 1][ar] = a0.y;
    As[ac + 2][ar] = a0.z; As[ac + 3][ar] = a0.w;
    As[ac + 0][ar + 64] = a1.x; As[ac + 1][ar + 64] = a1.y;
    As[ac + 2][ar + 64] = a1.z; As[ac + 3][ar + 64] = a1.w;
    *(float4*)&Bs[br][bc] = b0;
    *(float4*)&Bs[br + 8][bc] = b1;
    __syncthreads();
#pragma unroll
    for (int kk = 0; kk < BKK; ++kk) {
      float a_[8], b_[8];
      *(float4*)&a_[0] = *(const float4*)&As[kk][ty * 8];
      *(float4*)&a_[4] = *(const float4*)&As[kk][ty * 8 + 4];
      *(float4*)&b_[0] = *(const float4*)&Bs[kk][tx * 8];
      *(float4*)&b_[4] = *(const float4*)&Bs[kk][tx * 8 + 4];
#pragma unroll
      for (int i = 0; i < 8; ++i)
#pragma unroll
        for (int j = 0; j < 8; ++j) acc[i][j] += a_[i] * b_[j];
    }
  }

  // epilogue: + bias, relu, store
#pragma unroll
  for (int i = 0; i < 8; ++i) {
    const int row = M0 + ty * 8 + i;
    float* zr = Z + (size_t)row * DSAE;
#pragma unroll
    for (int j = 0; j < 8; j += 4) {
      const int col = N0 + tx * 8 + j;
      float4 v;
      v.x = fmaxf(acc[i][j + 0] + benc[col + 0], 0.f);
      v.y = fmaxf(acc[i][j + 1] + benc[col + 1], 0.f);
      v.z = fmaxf(acc[i][j + 2] + benc[col + 2], 0.f);
      v.w = fmaxf(acc[i][j + 3] + benc[col + 3], 0.f);
      *(float4*)&zr[col] = v;
    }
  }
}

// ---------------- Kernel 2: per-row exact top-64 mask (radix select) ----------------
// All values >= 0 after relu, so float bits order like uint32. 3 passes:
// bits[31:21] (2048 buckets), bits[20:10] (2048), bits[9:0] (1024) -> exact
// 64th-largest key. Ties at threshold broken by lowest index (top_k semantics).
__global__ __launch_bounds__(256) void topk_kernel(float* __restrict__ Z) {
  const int row = blockIdx.x;
  float* zrow = Z + (size_t)row * DSAE;
  __shared__ uint32_t hist[2048];
  __shared__ uint32_t gsum[256];
  __shared__ uint32_t s_sel, s_need;
  __shared__ int s_eqCnt;
  __shared__ int s_eqIdx[128];
  const int tid = threadIdx.x;

  uint32_t keys[64];
#pragma unroll
  for (int i = 0; i < 64; ++i)
    keys[i] = __float_as_uint(zrow[tid + (i << 8)]);

  // ---- pass 1: bits [31:21]
  for (int i = tid; i < 2048; i += 256) hist[i] = 0;
  __syncthreads();
#pragma unroll
  for (int i = 0; i < 64; ++i) atomicAdd(&hist[keys[i] >> 21], 1u);
  __syncthreads();
  {
    uint32_t s = 0;
#pragma unroll
    for (int j = 0; j < 8; ++j) s += hist[tid * 8 + j];
    gsum[tid] = s;
  }
  __syncthreads();
  if (tid == 0) {
    uint32_t k = 64, cum = 0;
    int g = 255;
    for (; g > 0; --g) {
      if (cum + gsum[g] >= k) break;
      cum += gsum[g];
    }
    int b = g * 8;
    for (int j = 7; j >= 0; --j) {
      uint32_t c = hist[g * 8 + j];
      if (cum + c >= k) { b = g * 8 + j; break; }
      cum += c;
    }
    s_sel = (uint32_t)b;
    s_need = k - cum;
  }
  __syncthreads();
  const uint32_t b1 = s_sel;
  uint32_t kneed = s_need;
  __syncthreads();

  // ---- pass 2: bits [20:10] among prefix b1
  for (int i = tid; i < 2048; i += 256) hist[i] = 0;
  __syncthreads();
#pragma unroll
  for (int i = 0; i < 64; ++i)
    if ((keys[i] >> 21) == b1) atomicAdd(&hist[(keys[i] >> 10) & 0x7FF], 1u);
  __syncthreads();
  {
    uint32_t s = 0;
#pragma unroll
    for (int j = 0; j < 8; ++j) s += hist[tid * 8 + j];
    gsum[tid] = s;
  }
  __syncthreads();
  if (tid == 0) {
    uint32_t k = kneed, cum = 0;
    int g = 255;
    for (; g > 0; --g) {
      if (cum + gsum[g] >= k) break;
      cum += gsum[g];
    }
    int b = g * 8;
    for (int j = 7; j >= 0; --j) {
      uint32_t c = hist[g * 8 + j];
      if (cum + c >= k) { b = g * 8 + j; break; }
      cum += c;
    }
    s_sel = (uint32_t)b;
    s_need = k - cum;
  }
  __syncthreads();
  const uint32_t pre21 = (b1 << 11) | s_sel;  // == key >> 10 for prefix class
  kneed = s_need;
  __syncthreads();

  // ---- pass 3: bits [9:0] among prefix pre21 (1024 buckets)
  for (int i = tid; i < 1024; i += 256) hist[i] = 0;
  __syncthreads();
#pragma unroll
  for (int i = 0; i < 64; ++i)
    if ((keys[i] >> 10) == pre21) atomicAdd(&hist[keys[i] & 0x3FF], 1u);
  __syncthreads();
  {
    uint32_t s = 0;
#pragma unroll
    for (int j = 0; j < 4; ++j) s += hist[tid * 4 + j];
    gsum[tid] = s;
  }
  __syncthreads();
  if (tid == 0) {
    uint32_t k = kneed, cum = 0;
    int g = 255;
    for (; g > 0; --g) {
      if (cum + gsum[g] >= k) break;
      cum += gsum[g];
    }
    int b = g * 4;
    for (int j = 3; j >= 0; --j) {
      uint32_t c = hist[g * 4 + j];
      if (cum + c >= k) { b = g * 4 + j; break; }
      cum += c;
    }
    s_sel = (uint32_t)b;
    s_need = k - cum;   // how many elements EQUAL to threshold to keep
    s_eqCnt = 0;
  }
  __syncthreads();
  const uint32_t thr = (pre21 << 10) | s_sel;
  const uint32_t Eneed = s_need;

  // collect indices of elements equal to threshold (tie-break: lowest index)
  if (thr != 0) {
#pragma unroll
    for (int i = 0; i < 64; ++i) {
      if (keys[i] == thr) {
        int p = atomicAdd(&s_eqCnt, 1);
        if (p < 128) s_eqIdx[p] = tid + (i << 8);
      }
    }
  }
  __syncthreads();
  const int eqc = min(s_eqCnt, 128);

  // write pass: keep k > thr always; k == thr kept for the Eneed lowest indices
#pragma unroll
  for (int i = 0; i < 64; ++i) {
    const uint32_t k = keys[i];
    float v = 0.f;
    if (k > thr) {
      v = __uint_as_float(k);
    } else if (thr != 0 && k == thr) {
      const int myidx = tid + (i << 8);
      int rank = 0;
      for (int j = 0; j < eqc; ++j) rank += (s_eqIdx[j] < myidx) ? 1 : 0;
      if (rank < (int)Eneed) v = __uint_as_float(k);
    }
    zrow[tid + (i << 8)] = v;
  }
}

// ---------------- Kernel 3: sparse decode  x_hat = z @ W_dec + b_dec ----------------
// One block per batch element. Compact nonzeros of z-row, then 64-term sparse
// accumulation per output element, float4-vectorized over d_in.
__global__ __launch_bounds__(256) void decode_kernel(
    const float* __restrict__ Z, const float* __restrict__ Wdec,
    const float* __restrict__ bdec, float* __restrict__ Xhat) {
  const int b = blockIdx.x;
  __shared__ float s_val[64];
  __shared__ int s_idx[64];
  __shared__ int s_cnt;
  if (threadIdx.x == 0) s_cnt = 0;
  __syncthreads();
  const float* z = Z + (size_t)b * DSAE;
  for (int i = threadIdx.x; i < DSAE; i += 256) {
    const float v = z[i];
    if (v > 0.0f) {
      int p = atomicAdd(&s_cnt, 1);
      if (p < KTOT) { s_idx[p] = i; s_val[p] = v; }
    }
  }
  __syncthreads();
  const int cnt = min(s_cnt, KTOT);

  // 3072 outputs = 768 float4; 3 per thread
  for (int o4 = threadIdx.x; o4 < (TT * DIN) / 4; o4 += 256) {
    const int t = o4 / (DIN / 4);           // 192 float4 per t
    const int d4 = o4 - t * (DIN / 4);
    const float* wt = Wdec + (size_t)t * DSAE * DIN + d4 * 4;
    float4 acc = *(const float4*)&bdec[o4 * 4];
    for (int j = 0; j < cnt; ++j) {
      const float4 w = *(const float4*)&wt[(size_t)s_idx[j] * DIN];
      const float vv = s_val[j];
      acc.x += vv * w.x;
      acc.y += vv * w.y;
      acc.z += vv * w.z;
      acc.w += vv * w.w;
    }
    *(float4*)&Xhat[(size_t)b * (TT * DIN) + o4 * 4] = acc;
  }
}

extern "C" void kernel_launch(void* const* d_in, const int* in_sizes, int n_in,
                              void* d_out, int out_size, void* d_ws, size_t ws_size,
                              hipStream_t stream) {
  const float* x = (const float*)d_in[0];      // (NB, TT, DIN)
  const float* W_enc = (const float*)d_in[1];  // (TT, DIN, DSAE)
  const float* b_enc = (const float*)d_in[2];  // (DSAE,)
  const float* W_dec = (const float*)d_in[3];  // (TT, DSAE, DIN)
  const float* b_dec = (const float*)d_in[4];  // (TT, DIN)

  float* out = (float*)d_out;
  float* xhat = out;                              // NB*TT*DIN floats
  float* z = out + (size_t)NB * TT * DIN;         // NB*DSAE floats

  dim3 g1(DSAE / BN, NB / BM);  // (128, 8)
  gemm_relu_kernel<<<g1, 256, 0, stream>>>(x, W_enc, b_enc, z);
  topk_kernel<<<NB, 256, 0, stream>>>(z);
  decode_kernel<<<NB, 256, 0, stream>>>(z, W_dec, b_dec, xhat);
}

// Round 2
// 1304.792 us; speedup vs baseline: 1.3984x; 1.3984x over previous
//
#include <hip/hip_runtime.h>
#include <hip/hip_bf16.h>
#include <stdint.h>

// Problem constants
#define NB 1024           // batch
#define TT 4
#define DIN 768
#define DSAE 16384
#define KD (TT * DIN)     // 3072
#define KTOT 64

typedef __bf16 bf16x8 __attribute__((ext_vector_type(8)));
typedef __bf16 bf16x4 __attribute__((ext_vector_type(4)));
typedef float f32x4 __attribute__((ext_vector_type(4)));

// async global->LDS, 16B per lane. lptr must be wave-uniform; HW scatters
// lane i to lptr + i*16.
__device__ __forceinline__ void gload_lds16(const void* g, void* l) {
  __builtin_amdgcn_global_load_lds(
      (const __attribute__((address_space(1))) void*)g,
      (__attribute__((address_space(3))) void*)l, 16, 0, 0);
}

// exact 3-term bf16 split (Sterbenz: residuals exact in fp32)
__device__ __forceinline__ void split3(float x, __bf16& o1, __bf16& o2, __bf16& o3) {
  __bf16 h1 = (__bf16)x;
  float r1 = x - (float)h1;
  __bf16 h2 = (__bf16)r1;
  float r2 = r1 - (float)h2;
  __bf16 h3 = (__bf16)r2;
  o1 = h1; o2 = h2; o3 = h3;
}

// ---------------- Split+transpose W_enc: (KD, DSAE) fp32 -> 3x (DSAE, KD) bf16 ----------------
__global__ __launch_bounds__(256) void split_w_kernel(
    const float* __restrict__ W, __bf16* __restrict__ W1,
    __bf16* __restrict__ W2, __bf16* __restrict__ W3) {
  __shared__ float tile[64][65];
  const int n0 = blockIdx.x * 64;  // 256 blocks
  const int k0 = blockIdx.y * 64;  // 48 blocks
  const int tid = threadIdx.x;
  {
    const int c4 = tid & 15;   // float4 col within tile
    const int r = tid >> 4;    // 0..15
#pragma unroll
    for (int it = 0; it < 4; ++it) {
      const int row = r + it * 16;  // k within tile
      const float4 v = *(const float4*)&W[(size_t)(k0 + row) * DSAE + n0 + c4 * 4];
      tile[row][c4 * 4 + 0] = v.x;
      tile[row][c4 * 4 + 1] = v.y;
      tile[row][c4 * 4 + 2] = v.z;
      tile[row][c4 * 4 + 3] = v.w;
    }
  }
  __syncthreads();
  {
    const int k4 = tid & 15;   // k float4 group
    const int r = tid >> 4;
#pragma unroll
    for (int it = 0; it < 4; ++it) {
      const int n = r + it * 16;
      bf16x4 v1, v2, v3;
#pragma unroll
      for (int j = 0; j < 4; ++j) {
        const float x = tile[k4 * 4 + j][n];
        __bf16 a, b, c;
        split3(x, a, b, c);
        v1[j] = a; v2[j] = b; v3[j] = c;
      }
      const size_t off = (size_t)(n0 + n) * KD + k0 + k4 * 4;
      *(bf16x4*)&W1[off] = v1;
      *(bf16x4*)&W2[off] = v2;
      *(bf16x4*)&W3[off] = v3;
    }
  }
}

// ---------------- Split x: (NB, KD) fp32 -> 3x (NB, KD) bf16 ----------------
__global__ __launch_bounds__(256) void split_x_kernel(
    const float* __restrict__ X, __bf16* __restrict__ X1,
    __bf16* __restrict__ X2, __bf16* __restrict__ X3) {
  const size_t i4 = (size_t)blockIdx.x * 256 + threadIdx.x;  // float4 index
  const float4 v = *(const float4*)&X[i4 * 4];
  bf16x4 v1, v2, v3;
  const float xs[4] = {v.x, v.y, v.z, v.w};
#pragma unroll
  for (int j = 0; j < 4; ++j) {
    __bf16 a, b, c;
    split3(xs[j], a, b, c);
    v1[j] = a; v2[j] = b; v3[j] = c;
  }
  *(bf16x4*)&X1[i4 * 4] = v1;
  *(bf16x4*)&X2[i4 * 4] = v2;
  *(bf16x4*)&X3[i4 * 4] = v3;
}

// ---------------- 6-pass split-bf16 MFMA GEMM: pre = relu(x*W + b) ----------------
// A[t]: (NB, KD) bf16 row-major. B[t]: (DSAE, KD) bf16 row-major (n-major!).
// 128x128 tile, BK=32, 4 waves (2x2 of 64x64 wave-tiles), 16x16x32 MFMA.
__global__ __launch_bounds__(256, 2) void gemm_split_kernel(
    const __bf16* __restrict__ A1, const __bf16* __restrict__ A2,
    const __bf16* __restrict__ A3, const __bf16* __restrict__ B1,
    const __bf16* __restrict__ B2, const __bf16* __restrict__ B3,
    const float* __restrict__ benc, float* __restrict__ Z) {
  __shared__ __bf16 sA[3][128 * 32];
  __shared__ __bf16 sB[3][128 * 32];
  const int tid = threadIdx.x;
  const int wave = tid >> 6, lane = tid & 63;
  const int M0 = blockIdx.x * 128;  // 8 m-blocks (fastest -> W-slice L3 reuse)
  const int N0 = blockIdx.y * 128;  // 128 n-blocks
  const int wm = (wave & 1) * 64, wn = (wave >> 1) * 64;

  // staging source: each thread loads 16B (8 bf16 along k)
  const int srow = tid >> 2;          // 0..63
  const int scol = (tid & 3) * 8;     // k offset 0,8,16,24
  const __bf16* gA[3] = {A1 + (size_t)(M0 + srow) * KD + scol,
                         A2 + (size_t)(M0 + srow) * KD + scol,
                         A3 + (size_t)(M0 + srow) * KD + scol};
  const __bf16* gB[3] = {B1 + (size_t)(N0 + srow) * KD + scol,
                         B2 + (size_t)(N0 + srow) * KD + scol,
                         B3 + (size_t)(N0 + srow) * KD + scol};

  f32x4 acc[4][4];
#pragma unroll
  for (int i = 0; i < 4; ++i)
#pragma unroll
    for (int j = 0; j < 4; ++j) acc[i][j] = (f32x4){0.f, 0.f, 0.f, 0.f};

  const int frow = lane & 15;
  const int fk = (lane >> 4) * 8;

  for (int k0 = 0; k0 < KD; k0 += 32) {
    __syncthreads();  // prev iter's LDS reads complete before overwrite
#pragma unroll
    for (int r = 0; r < 2; ++r) {
      const size_t goff = (size_t)k0 + (size_t)r * 64 * KD;
      const int loff = wave * 512 + r * 2048;
#pragma unroll
      for (int t = 0; t < 3; ++t) {
        gload_lds16(gA[t] + goff, &sA[t][loff]);
        gload_lds16(gB[t] + goff, &sB[t][loff]);
      }
    }
    __syncthreads();  // drains vmcnt(0): LDS tiles ready

    bf16x8 af[3][4];
#pragma unroll
    for (int mi = 0; mi < 4; ++mi) {
      const int ao = (wm + mi * 16 + frow) * 32 + fk;
#pragma unroll
      for (int t = 0; t < 3; ++t)
        af[t][mi] = *(const bf16x8*)&sA[t][ao];
    }
#pragma unroll
    for (int ni = 0; ni < 4; ++ni) {
      const int bo = (wn + ni * 16 + frow) * 32 + fk;
      const bf16x8 b1 = *(const bf16x8*)&sB[0][bo];
      const bf16x8 b2 = *(const bf16x8*)&sB[1][bo];
      const bf16x8 b3 = *(const bf16x8*)&sB[2][bo];
#pragma unroll
      for (int mi = 0; mi < 4; ++mi) {
        f32x4 c = acc[mi][ni];
        c = __builtin_amdgcn_mfma_f32_16x16x32_bf16(af[0][mi], b1, c, 0, 0, 0);
        c = __builtin_amdgcn_mfma_f32_16x16x32_bf16(af[0][mi], b2, c, 0, 0, 0);
        c = __builtin_amdgcn_mfma_f32_16x16x32_bf16(af[1][mi], b1, c, 0, 0, 0);
        c = __builtin_amdgcn_mfma_f32_16x16x32_bf16(af[1][mi], b2, c, 0, 0, 0);
        c = __builtin_amdgcn_mfma_f32_16x16x32_bf16(af[0][mi], b3, c, 0, 0, 0);
        c = __builtin_amdgcn_mfma_f32_16x16x32_bf16(af[2][mi], b1, c, 0, 0, 0);
        acc[mi][ni] = c;
      }
    }
  }

  // epilogue: C/D layout col=lane&15, row=(lane>>4)*4+reg  [m89/m91-verified]
#pragma unroll
  for (int ni = 0; ni < 4; ++ni) {
    const int col = N0 + wn + ni * 16 + (lane & 15);
    const float bias = benc[col];
#pragma unroll
    for (int mi = 0; mi < 4; ++mi) {
      const int rbase = M0 + wm + mi * 16 + (lane >> 4) * 4;
#pragma unroll
      for (int r = 0; r < 4; ++r)
        Z[(size_t)(rbase + r) * DSAE + col] = fmaxf(acc[mi][ni][r] + bias, 0.f);
    }
  }
}

// ---------------- fp32 fallback GEMM (round-1, proven) ----------------
#define BM 128
#define BN 128
#define BKK 16
__global__ __launch_bounds__(256, 2) void gemm_relu_kernel(
    const float* __restrict__ A, const float* __restrict__ W,
    const float* __restrict__ benc, float* __restrict__ Z) {
  __shared__ float As[BKK][BM + 4];
  __shared__ float Bs[BKK][BN + 4];
  const int tid = threadIdx.x;
  const int bn = blockIdx.x;
  const int bm = blockIdx.y;
  const int M0 = bm * BM, N0 = bn * BN;
  const int tx = tid & 15, ty = tid >> 4;
  const int ar = tid >> 2;
  const int ac = (tid & 3) << 2;
  const int br = tid >> 5;
  const int bc = (tid & 31) << 2;
  float acc[8][8];
#pragma unroll
  for (int i = 0; i < 8; ++i)
#pragma unroll
    for (int j = 0; j < 8; ++j) acc[i][j] = 0.f;
  for (int k0 = 0; k0 < KD; k0 += BKK) {
    const float4 a0 = *(const float4*)&A[(size_t)(M0 + ar) * KD + k0 + ac];
    const float4 a1 = *(const float4*)&A[(size_t)(M0 + ar + 64) * KD + k0 + ac];
    const float4 b0 = *(const float4*)&W[(size_t)(k0 + br) * DSAE + N0 + bc];
    const float4 b1 = *(const float4*)&W[(size_t)(k0 + br + 8) * DSAE + N0 + bc];
    __syncthreads();
    As[ac + 0][ar] = a0.x; As[ac + 1][ar] = a0.y;
    As[ac + 2][ar] = a0.z; As[ac + 3][ar] = a0.w;
    As[ac + 0][ar + 64] = a1.x; As[ac + 1][ar + 64] = a1.y;
    As[ac + 2][ar + 64] = a1.z; As[ac + 3][ar + 64] = a1.w;
    *(float4*)&Bs[br][bc] = b0;
    *(float4*)&Bs[br + 8][bc] = b1;
    __syncthreads();
#pragma unroll
    for (int kk = 0; kk < BKK; ++kk) {
      float a_[8], b_[8];
      *(float4*)&a_[0] = *(const float4*)&As[kk][ty * 8];
      *(float4*)&a_[4] = *(const float4*)&As[kk][ty * 8 + 4];
      *(float4*)&b_[0] = *(const float4*)&Bs[kk][tx * 8];
      *(float4*)&b_[4] = *(const float4*)&Bs[kk][tx * 8 + 4];
#pragma unroll
      for (int i = 0; i < 8; ++i)
#pragma unroll
        for (int j = 0; j < 8; ++j) acc[i][j] += a_[i] * b_[j];
    }
  }
#pragma unroll
  for (int i = 0; i < 8; ++i) {
    const int row = M0 + ty * 8 + i;
    float* zr = Z + (size_t)row * DSAE;
#pragma unroll
    for (int j = 0; j < 8; j += 4) {
      const int col = N0 + tx * 8 + j;
      float4 v;
      v.x = fmaxf(acc[i][j + 0] + benc[col + 0], 0.f);
      v.y = fmaxf(acc[i][j + 1] + benc[col + 1], 0.f);
      v.z = fmaxf(acc[i][j + 2] + benc[col + 2], 0.f);
      v.w = fmaxf(acc[i][j + 3] + benc[col + 3], 0.f);
      *(float4*)&zr[col] = v;
    }
  }
}

// ---------------- per-row exact top-64 mask (radix select) + compaction ----------------
__global__ __launch_bounds__(256) void topk_kernel(float* __restrict__ Z,
                                                   int* __restrict__ cidx,
                                                   float* __restrict__ cval) {
  const int row = blockIdx.x;
  float* zrow = Z + (size_t)row * DSAE;
  __shared__ uint32_t hist[2048];
  __shared__ uint32_t gsum[256];
  __shared__ uint32_t s_sel, s_need;
  __shared__ int s_eqCnt;
  __shared__ int s_eqIdx[128];
  __shared__ int s_outCnt;
  const int tid = threadIdx.x;

  uint32_t keys[64];
#pragma unroll
  for (int i = 0; i < 64; ++i)
    keys[i] = __float_as_uint(zrow[tid + (i << 8)]);

  // pass 1: bits [31:21]
  for (int i = tid; i < 2048; i += 256) hist[i] = 0;
  if (tid == 0) s_outCnt = 0;
  __syncthreads();
#pragma unroll
  for (int i = 0; i < 64; ++i) atomicAdd(&hist[keys[i] >> 21], 1u);
  __syncthreads();
  {
    uint32_t s = 0;
#pragma unroll
    for (int j = 0; j < 8; ++j) s += hist[tid * 8 + j];
    gsum[tid] = s;
  }
  __syncthreads();
  if (tid == 0) {
    uint32_t k = 64, cum = 0;
    int g = 255;
    for (; g > 0; --g) {
      if (cum + gsum[g] >= k) break;
      cum += gsum[g];
    }
    int b = g * 8;
    for (int j = 7; j >= 0; --j) {
      uint32_t c = hist[g * 8 + j];
      if (cum + c >= k) { b = g * 8 + j; break; }
      cum += c;
    }
    s_sel = (uint32_t)b;
    s_need = k - cum;
  }
  __syncthreads();
  const uint32_t b1 = s_sel;
  uint32_t kneed = s_need;
  __syncthreads();

  // pass 2: bits [20:10]
  for (int i = tid; i < 2048; i += 256) hist[i] = 0;
  __syncthreads();
#pragma unroll
  for (int i = 0; i < 64; ++i)
    if ((keys[i] >> 21) == b1) atomicAdd(&hist[(keys[i] >> 10) & 0x7FF], 1u);
  __syncthreads();
  {
    uint32_t s = 0;
#pragma unroll
    for (int j = 0; j < 8; ++j) s += hist[tid * 8 + j];
    gsum[tid] = s;
  }
  __syncthreads();
  if (tid == 0) {
    uint32_t k = kneed, cum = 0;
    int g = 255;
    for (; g > 0; --g) {
      if (cum + gsum[g] >= k) break;
      cum += gsum[g];
    }
    int b = g * 8;
    for (int j = 7; j >= 0; --j) {
      uint32_t c = hist[g * 8 + j];
      if (cum + c >= k) { b = g * 8 + j; break; }
      cum += c;
    }
    s_sel = (uint32_t)b;
    s_need = k - cum;
  }
  __syncthreads();
  const uint32_t pre21 = (b1 << 11) | s_sel;
  kneed = s_need;
  __syncthreads();

  // pass 3: bits [9:0]
  for (int i = tid; i < 1024; i += 256) hist[i] = 0;
  __syncthreads();
#pragma unroll
  for (int i = 0; i < 64; ++i)
    if ((keys[i] >> 10) == pre21) atomicAdd(&hist[keys[i] & 0x3FF], 1u);
  __syncthreads();
  {
    uint32_t s = 0;
#pragma unroll
    for (int j = 0; j < 4; ++j) s += hist[tid * 4 + j];
    gsum[tid] = s;
  }
  __syncthreads();
  if (tid == 0) {
    uint32_t k = kneed, cum = 0;
    int g = 255;
    for (; g > 0; --g) {
      if (cum + gsum[g] >= k) break;
      cum += gsum[g];
    }
    int b = g * 4;
    for (int j = 3; j >= 0; --j) {
      uint32_t c = hist[g * 4 + j];
      if (cum + c >= k) { b = g * 4 + j; break; }
      cum += c;
    }
    s_sel = (uint32_t)b;
    s_need = k - cum;
    s_eqCnt = 0;
  }
  __syncthreads();
  const uint32_t thr = (pre21 << 10) | s_sel;
  const uint32_t Eneed = s_need;

  if (thr != 0) {
#pragma unroll
    for (int i = 0; i < 64; ++i) {
      if (keys[i] == thr) {
        int p = atomicAdd(&s_eqCnt, 1);
        if (p < 128) s_eqIdx[p] = tid + (i << 8);
      }
    }
  }
  __syncthreads();
  const int eqc = min(s_eqCnt, 128);

#pragma unroll
  for (int i = 0; i < 64; ++i) {
    const uint32_t k = keys[i];
    float v = 0.f;
    if (k > thr) {
      v = __uint_as_float(k);
    } else if (thr != 0 && k == thr) {
      const int myidx = tid + (i << 8);
      int rank = 0;
      for (int j = 0; j < eqc; ++j) rank += (s_eqIdx[j] < myidx) ? 1 : 0;
      if (rank < (int)Eneed) v = __uint_as_float(k);
    }
    zrow[tid + (i << 8)] = v;
    if (cidx != nullptr && v != 0.f) {
      const int p = atomicAdd(&s_outCnt, 1);
      if (p < KTOT) {
        cidx[row * KTOT + p] = tid + (i << 8);
        cval[row * KTOT + p] = v;
      }
    }
  }
  if (cidx != nullptr) {
    __syncthreads();
    for (int p = s_outCnt + tid; p < KTOT; p += 256) {
      cidx[row * KTOT + p] = 0;
      cval[row * KTOT + p] = 0.f;
    }
  }
}

// ---------------- decode v2: block per (b,t), fixed-64 unrolled candidates ----------------
__global__ __launch_bounds__(192) void decode2_kernel(
    const int* __restrict__ cidx, const float* __restrict__ cval,
    const float* __restrict__ Wdec, const float* __restrict__ bdec,
    float* __restrict__ Xhat) {
  const int b = blockIdx.x, t = blockIdx.y;
  __shared__ float sv[KTOT];
  __shared__ int si[KTOT];
  if (threadIdx.x < KTOT) {
    sv[threadIdx.x] = cval[b * KTOT + threadIdx.x];
    si[threadIdx.x] = cidx[b * KTOT + threadIdx.x];
  }
  __syncthreads();
  const int d4 = threadIdx.x;  // 0..191 float4 outputs
  const float* wt = Wdec + (size_t)t * DSAE * DIN + d4 * 4;
  float4 acc = *(const float4*)&bdec[t * DIN + d4 * 4];
#pragma unroll 8
  for (int j = 0; j < KTOT; ++j) {
    const float4 w = *(const float4*)&wt[(size_t)si[j] * DIN];
    const float vv = sv[j];
    acc.x += vv * w.x;
    acc.y += vv * w.y;
    acc.z += vv * w.z;
    acc.w += vv * w.w;
  }
  *(float4*)&Xhat[(size_t)b * (TT * DIN) + t * DIN + d4 * 4] = acc;
}

// ---------------- decode fallback (round-1, proven; scans dense z) ----------------
__global__ __launch_bounds__(256) void decode_kernel(
    const float* __restrict__ Z, const float* __restrict__ Wdec,
    const float* __restrict__ bdec, float* __restrict__ Xhat) {
  const int b = blockIdx.x;
  __shared__ float s_val[64];
  __shared__ int s_idx[64];
  __shared__ int s_cnt;
  if (threadIdx.x == 0) s_cnt = 0;
  __syncthreads();
  const float* z = Z + (size_t)b * DSAE;
  for (int i = threadIdx.x; i < DSAE; i += 256) {
    const float v = z[i];
    if (v > 0.0f) {
      int p = atomicAdd(&s_cnt, 1);
      if (p < KTOT) { s_idx[p] = i; s_val[p] = v; }
    }
  }
  __syncthreads();
  const int cnt = min(s_cnt, KTOT);
  for (int o4 = threadIdx.x; o4 < (TT * DIN) / 4; o4 += 256) {
    const int t = o4 / (DIN / 4);
    const int d4 = o4 - t * (DIN / 4);
    const float* wt = Wdec + (size_t)t * DSAE * DIN + d4 * 4;
    float4 acc = *(const float4*)&bdec[o4 * 4];
    for (int j = 0; j < cnt; ++j) {
      const float4 w = *(const float4*)&wt[(size_t)s_idx[j] * DIN];
      const float vv = s_val[j];
      acc.x += vv * w.x;
      acc.y += vv * w.y;
      acc.z += vv * w.z;
      acc.w += vv * w.w;
    }
    *(float4*)&Xhat[(size_t)b * (TT * DIN) + o4 * 4] = acc;
  }
}

extern "C" void kernel_launch(void* const* d_in, const int* in_sizes, int n_in,
                              void* d_out, int out_size, void* d_ws, size_t ws_size,
                              hipStream_t stream) {
  const float* x = (const float*)d_in[0];      // (NB, TT, DIN)
  const float* W_enc = (const float*)d_in[1];  // (TT, DIN, DSAE) == (KD, DSAE)
  const float* b_enc = (const float*)d_in[2];  // (DSAE,)
  const float* W_dec = (const float*)d_in[3];  // (TT, DSAE, DIN)
  const float* b_dec = (const float*)d_in[4];  // (TT, DIN)

  float* out = (float*)d_out;
  float* xhat = out;                       // NB*TT*DIN
  float* z = out + (size_t)NB * TT * DIN;  // NB*DSAE

  const size_t W_TERM = (size_t)KD * DSAE * 2;      // 100663296 B
  const size_t X_TERM = (size_t)NB * KD * 2;        // 6291456 B
  const size_t CAND_I = (size_t)NB * KTOT * 4;      // 262144 B
  const size_t NEED_A = 3 * W_TERM + 3 * X_TERM + 2 * CAND_I;
  const size_t NEED_B = 2 * CAND_I;

  char* ws = (char*)d_ws;
  if (ws_size >= NEED_A) {
    __bf16* W1 = (__bf16*)(ws + 0 * W_TERM);
    __bf16* W2 = (__bf16*)(ws + 1 * W_TERM);
    __bf16* W3 = (__bf16*)(ws + 2 * W_TERM);
    __bf16* X1 = (__bf16*)(ws + 3 * W_TERM + 0 * X_TERM);
    __bf16* X2 = (__bf16*)(ws + 3 * W_TERM + 1 * X_TERM);
    __bf16* X3 = (__bf16*)(ws + 3 * W_TERM + 2 * X_TERM);
    int* cidx = (int*)(ws + 3 * W_TERM + 3 * X_TERM);
    float* cval = (float*)(ws + 3 * W_TERM + 3 * X_TERM + CAND_I);

    split_w_kernel<<<dim3(DSAE / 64, KD / 64), 256, 0, stream>>>(W_enc, W1, W2, W3);
    split_x_kernel<<<(NB * KD / 4) / 256, 256, 0, stream>>>(x, X1, X2, X3);
    gemm_split_kernel<<<dim3(NB / 128, DSAE / 128), 256, 0, stream>>>(
        X1, X2, X3, W1, W2, W3, b_enc, z);
    topk_kernel<<<NB, 256, 0, stream>>>(z, cidx, cval);
    decode2_kernel<<<dim3(NB, TT), 192, 0, stream>>>(cidx, cval, W_dec, b_dec, xhat);
  } else if (ws_size >= NEED_B) {
    int* cidx = (int*)ws;
    float* cval = (float*)(ws + CAND_I);
    gemm_relu_kernel<<<dim3(DSAE / BN, NB / BM), 256, 0, stream>>>(x, W_enc, b_enc, z);
    topk_kernel<<<NB, 256, 0, stream>>>(z, cidx, cval);
    decode2_kernel<<<dim3(NB, TT), 192, 0, stream>>>(cidx, cval, W_dec, b_dec, xhat);
  } else {
    gemm_relu_kernel<<<dim3(DSAE / BN, NB / BM), 256, 0, stream>>>(x, W_enc, b_enc, z);
    topk_kernel<<<NB, 256, 0, stream>>>(z, nullptr, nullptr);
    decode_kernel<<<NB, 256, 0, stream>>>(z, W_dec, b_dec, xhat);
  }
}